// Round 1
// baseline (28197.110 us; speedup 1.0000x reference)
//
#include <hip/hip_runtime.h>
#include <stdint.h>

#define NB 64
#define NT 2048
#define ND 1024
#define NU 1024

typedef __attribute__((ext_vector_type(8))) short bf16x8;
typedef __attribute__((ext_vector_type(4))) float f32x4;

__device__ __forceinline__ unsigned short f2bf(float f) {
  union { float f; unsigned u; } v; v.f = f;
  return (unsigned short)((v.u + 0x7FFFu + ((v.u >> 16) & 1u)) >> 16);
}
__device__ __forceinline__ float bf2f(unsigned short s) {
  union { unsigned u; float f; } v; v.u = ((unsigned)s) << 16; return v.f;
}

// ---------------- init: zero barrier area + h double-buffer ----------------
__global__ void init_ws(unsigned* __restrict__ ws) {
  const int n = 1024 + (2 * NB * NU) / 2;  // 1024 uints barrier + 65536 uints hbuf
  for (int i = blockIdx.x * blockDim.x + threadIdx.x; i < n; i += gridDim.x * blockDim.x)
    ws[i] = 0u;
}

// ---------------- xp = inputs @ W_x + b  (bf16 MFMA, 128x128 tile) ----------------
__launch_bounds__(256, 3)
__global__ void gemm_xp(const float* __restrict__ inp, const float* __restrict__ Wx,
                        const float* __restrict__ bias, float* __restrict__ xp,
                        int t0, int Tc) {
  __shared__ unsigned short As[128][56];  // [m][k] padded: stride 112B, 2-way banks
  __shared__ unsigned short Bs[128][56];  // [u][k] (transposed W_x), same padding

  const int tid = threadIdx.x;
  const int u0 = blockIdx.x * 128;
  const int m_base = blockIdx.y * 128;
  const int b = m_base / Tc;           // Tc is a multiple of 128 -> tile stays in one batch
  const int tc0 = m_base % Tc;
  const size_t arow0 = ((size_t)b * NT + t0 + tc0) * (size_t)ND;

  const int w = tid >> 6, lane = tid & 63;
  const int wr = w >> 1, wc = w & 1;
  const int l15 = lane & 15, lk = lane >> 4;
  const int srow = tid & 127;
  const int shalf = tid >> 7;

  f32x4 acc[4][4];
  #pragma unroll
  for (int i = 0; i < 4; ++i)
    #pragma unroll
    for (int j = 0; j < 4; ++j)
      acc[i][j] = (f32x4){0.f, 0.f, 0.f, 0.f};

  for (int k0 = 0; k0 < ND; k0 += 32) {
    __syncthreads();
    {  // stage A: inputs fp32 -> bf16, row srow, k in [k0+shalf*16, +16)
      const float* src = inp + arow0 + (size_t)srow * ND + k0 + shalf * 16;
      unsigned short tmp[16];
      #pragma unroll
      for (int i = 0; i < 16; i += 4) {
        float4 v = *(const float4*)(src + i);
        tmp[i + 0] = f2bf(v.x); tmp[i + 1] = f2bf(v.y);
        tmp[i + 2] = f2bf(v.z); tmp[i + 3] = f2bf(v.w);
      }
      #pragma unroll
      for (int h = 0; h < 2; ++h) {
        bf16x8 pv;
        #pragma unroll
        for (int j = 0; j < 8; ++j) pv[j] = (short)tmp[h * 8 + j];
        *(bf16x8*)&As[srow][shalf * 16 + h * 8] = pv;
      }
    }
    {  // stage B: W_x fp32 -> bf16 transposed to [u][k]
      const float* src = Wx + (size_t)(k0 + shalf * 16) * NU + u0 + srow;
      unsigned short tmp[16];
      #pragma unroll
      for (int i = 0; i < 16; ++i) tmp[i] = f2bf(src[(size_t)i * NU]);
      #pragma unroll
      for (int h = 0; h < 2; ++h) {
        bf16x8 pv;
        #pragma unroll
        for (int j = 0; j < 8; ++j) pv[j] = (short)tmp[h * 8 + j];
        *(bf16x8*)&Bs[srow][shalf * 16 + h * 8] = pv;
      }
    }
    __syncthreads();

    bf16x8 af[4], bfr[4];
    #pragma unroll
    for (int mf = 0; mf < 4; ++mf)
      af[mf] = *(const bf16x8*)&As[wr * 64 + mf * 16 + l15][lk * 8];
    #pragma unroll
    for (int nf = 0; nf < 4; ++nf)
      bfr[nf] = *(const bf16x8*)&Bs[wc * 64 + nf * 16 + l15][lk * 8];
    #pragma unroll
    for (int mf = 0; mf < 4; ++mf)
      #pragma unroll
      for (int nf = 0; nf < 4; ++nf)
        acc[mf][nf] = __builtin_amdgcn_mfma_f32_16x16x32_bf16(af[mf], bfr[nf], acc[mf][nf], 0, 0, 0);
  }

  #pragma unroll
  for (int nf = 0; nf < 4; ++nf) {
    const int col = u0 + wc * 64 + nf * 16 + l15;
    const float bv = bias[col];
    #pragma unroll
    for (int mf = 0; mf < 4; ++mf) {
      const int rbase = m_base + wr * 64 + mf * 16 + lk * 4;
      #pragma unroll
      for (int r = 0; r < 4; ++r)
        xp[(size_t)(rbase + r) * NU + col] = acc[mf][nf][r] + bv;
    }
  }
}

// ---------------- persistent recurrent scan ----------------
// 128 WGs: wid>>6 = batch half (32 rows), wid&63 = 16-column slice.
// W_h slice lives fragment-ordered in LDS for all steps. One tree barrier per step.
__launch_bounds__(256, 1)
__global__ void scan_kernel(const float* __restrict__ Wh, const float* __restrict__ xp,
                            unsigned short* __restrict__ hbuf, float* __restrict__ out,
                            unsigned* __restrict__ bar, int t0, int Tc) {
  __shared__ unsigned short Wf[32][512];  // [kk][lane*8+j] fragment-ordered bf16 (32 KB)
  __shared__ f32x4 Red[4][2][64];         // cross-wave K-reduction (8 KB)

  const int tid = threadIdx.x;
  const int wid = blockIdx.x;
  const int bh = wid >> 6;
  const int col0 = (wid & 63) * 16;

  for (int idx = tid; idx < 16384; idx += 256) {
    const int k = idx >> 4, c = idx & 15;
    const float wv = Wh[(size_t)k * NU + col0 + c];
    const int kk = k >> 5, sub = k & 31;
    Wf[kk][(c + ((sub >> 3) << 4)) * 8 + (sub & 7)] = f2bf(wv);
  }
  __syncthreads();

  const int w = tid >> 6, lane = tid & 63;
  const int l15 = lane & 15, lk = lane >> 4;
  const int rowbase = bh * 32;

  for (int tc = 0; tc < Tc; ++tc) {
    const int t = t0 + tc;
    const unsigned short* __restrict__ hc = hbuf + (size_t)(t & 1) * (NB * NU);
    unsigned short* __restrict__ hn = hbuf + (size_t)((t + 1) & 1) * (NB * NU);

    float xpv[4] = {0.f, 0.f, 0.f, 0.f};
    if (w < 2) {
      #pragma unroll
      for (int r = 0; r < 4; ++r)
        xpv[r] = xp[((size_t)(rowbase + w * 16 + lk * 4 + r) * Tc + tc) * NU + col0 + l15];
    }

    // K-split: wave w covers kk in [8w, 8w+8) for both 16-row m-tiles
    f32x4 acc0 = {0.f, 0.f, 0.f, 0.f}, acc1 = {0.f, 0.f, 0.f, 0.f};
    const int kb = w * 8;
    #pragma unroll
    for (int kq = 0; kq < 8; ++kq) {
      const int kk = kb + kq;
      const bf16x8 bfr = *(const bf16x8*)&Wf[kk][lane * 8];
      const bf16x8 a0 = *(const bf16x8*)(hc + (size_t)(rowbase + l15) * NU + kk * 32 + lk * 8);
      const bf16x8 a1 = *(const bf16x8*)(hc + (size_t)(rowbase + 16 + l15) * NU + kk * 32 + lk * 8);
      acc0 = __builtin_amdgcn_mfma_f32_16x16x32_bf16(a0, bfr, acc0, 0, 0, 0);
      acc1 = __builtin_amdgcn_mfma_f32_16x16x32_bf16(a1, bfr, acc1, 0, 0, 0);
    }
    Red[w][0][lane] = acc0;
    Red[w][1][lane] = acc1;
    __syncthreads();

    if (w < 2) {  // waves 0,1 finish m-tile 0,1
      f32x4 z4 = Red[0][w][lane];
      z4 += Red[1][w][lane];
      z4 += Red[2][w][lane];
      z4 += Red[3][w][lane];
      #pragma unroll
      for (int r = 0; r < 4; ++r) {
        const float z = z4[r] + xpv[r];
        const float hv = tanhf(z);
        const size_t orow = (size_t)(rowbase + w * 16 + lk * 4 + r);
        hn[orow * NU + col0 + l15] = f2bf(hv);
        if (t == NT - 1) out[orow * NU + col0 + l15] = hv;
      }
    }

    if (tc != Tc - 1) {  // two-level tree barrier (16 groups x 8 WGs)
      __syncthreads();
      if (tid == 0) {
        unsigned* gen = bar + 544;
        const unsigned g = __hip_atomic_load(gen, __ATOMIC_RELAXED, __HIP_MEMORY_SCOPE_AGENT);
        unsigned* c1 = bar + (wid & 15) * 32;
        const unsigned a1 = __hip_atomic_fetch_add(c1, 1u, __ATOMIC_ACQ_REL, __HIP_MEMORY_SCOPE_AGENT);
        if (a1 == 7u) {
          __hip_atomic_store(c1, 0u, __ATOMIC_RELAXED, __HIP_MEMORY_SCOPE_AGENT);
          unsigned* c2 = bar + 512;
          const unsigned a2 = __hip_atomic_fetch_add(c2, 1u, __ATOMIC_ACQ_REL, __HIP_MEMORY_SCOPE_AGENT);
          if (a2 == 15u) {
            __hip_atomic_store(c2, 0u, __ATOMIC_RELAXED, __HIP_MEMORY_SCOPE_AGENT);
            __hip_atomic_store(gen, g + 1u, __ATOMIC_RELEASE, __HIP_MEMORY_SCOPE_AGENT);
          } else {
            while (__hip_atomic_load(gen, __ATOMIC_ACQUIRE, __HIP_MEMORY_SCOPE_AGENT) == g) {}
          }
        } else {
          while (__hip_atomic_load(gen, __ATOMIC_ACQUIRE, __HIP_MEMORY_SCOPE_AGENT) == g) {}
        }
      }
      __syncthreads();
    }
  }
}

extern "C" void kernel_launch(void* const* d_in, const int* in_sizes, int n_in,
                              void* d_out, int out_size, void* d_ws, size_t ws_size,
                              hipStream_t stream) {
  (void)in_sizes; (void)n_in; (void)out_size;
  const float* inp  = (const float*)d_in[0];
  const float* Wx   = (const float*)d_in[1];
  const float* Wh   = (const float*)d_in[2];
  const float* bias = (const float*)d_in[3];
  float* out = (float*)d_out;

  unsigned* bar = (unsigned*)d_ws;                                   // 4 KB barrier area
  unsigned short* hbuf = (unsigned short*)((char*)d_ws + 4096);      // 256 KB h double-buffer
  const size_t xp_off = 4096 + (size_t)2 * NB * NU * sizeof(unsigned short);
  float* xp = (float*)((char*)d_ws + xp_off);
  const size_t avail = (ws_size > xp_off) ? ws_size - xp_off : 0;

  int Tc = 128;  // chunk of timesteps whose xp fits in workspace (multiple of 128)
  for (int cand = NT; cand >= 128; cand >>= 1)
    if ((size_t)NB * (size_t)cand * NU * sizeof(float) <= avail) { Tc = cand; break; }

  init_ws<<<dim3(128), dim3(256), 0, stream>>>((unsigned*)d_ws);

  for (int t0 = 0; t0 < NT; t0 += Tc) {
    gemm_xp<<<dim3(8, (NB * Tc) / 128), dim3(256), 0, stream>>>(inp, Wx, bias, xp, t0, Tc);
    scan_kernel<<<dim3(128), dim3(256), 0, stream>>>(Wh, xp, hbuf, out, bar, t0, Tc);
  }
}

// Round 2
// 22999.306 us; speedup vs baseline: 1.2260x; 1.2260x over previous
//
#include <hip/hip_runtime.h>
#include <stdint.h>

#define NB 64
#define NT 2048
#define ND 1024
#define NU 1024

typedef __attribute__((ext_vector_type(8))) short bf16x8;
typedef __attribute__((ext_vector_type(4))) float f32x4;
typedef unsigned long long u64;

__device__ __forceinline__ unsigned short f2bf(float f) {
  union { float f; unsigned u; } v; v.f = f;
  return (unsigned short)((v.u + 0x7FFFu + ((v.u >> 16) & 1u)) >> 16);
}

// ---------------- init: zero barrier area + h double-buffer ----------------
__global__ void init_ws(unsigned* __restrict__ ws) {
  const int n = 1024 + (2 * NB * NU) / 2;  // 1024 uints barrier + 65536 uints hbuf
  for (int i = blockIdx.x * blockDim.x + threadIdx.x; i < n; i += gridDim.x * blockDim.x)
    ws[i] = 0u;
}

// ---------------- xp = inputs @ W_x + b  (bf16 MFMA, 128x128 tile) ----------------
__launch_bounds__(256, 3)
__global__ void gemm_xp(const float* __restrict__ inp, const float* __restrict__ Wx,
                        const float* __restrict__ bias, float* __restrict__ xp,
                        int t0, int Tc) {
  __shared__ unsigned short As[128][56];
  __shared__ unsigned short Bs[128][56];

  const int tid = threadIdx.x;
  const int u0 = blockIdx.x * 128;
  const int m_base = blockIdx.y * 128;
  const int b = m_base / Tc;
  const int tc0 = m_base % Tc;
  const size_t arow0 = ((size_t)b * NT + t0 + tc0) * (size_t)ND;

  const int w = tid >> 6, lane = tid & 63;
  const int wr = w >> 1, wc = w & 1;
  const int l15 = lane & 15, lk = lane >> 4;
  const int srow = tid & 127;
  const int shalf = tid >> 7;

  f32x4 acc[4][4];
  #pragma unroll
  for (int i = 0; i < 4; ++i)
    #pragma unroll
    for (int j = 0; j < 4; ++j)
      acc[i][j] = (f32x4){0.f, 0.f, 0.f, 0.f};

  for (int k0 = 0; k0 < ND; k0 += 32) {
    __syncthreads();
    {
      const float* src = inp + arow0 + (size_t)srow * ND + k0 + shalf * 16;
      unsigned short tmp[16];
      #pragma unroll
      for (int i = 0; i < 16; i += 4) {
        float4 v = *(const float4*)(src + i);
        tmp[i + 0] = f2bf(v.x); tmp[i + 1] = f2bf(v.y);
        tmp[i + 2] = f2bf(v.z); tmp[i + 3] = f2bf(v.w);
      }
      #pragma unroll
      for (int h = 0; h < 2; ++h) {
        bf16x8 pv;
        #pragma unroll
        for (int j = 0; j < 8; ++j) pv[j] = (short)tmp[h * 8 + j];
        *(bf16x8*)&As[srow][shalf * 16 + h * 8] = pv;
      }
    }
    {
      const float* src = Wx + (size_t)(k0 + shalf * 16) * NU + u0 + srow;
      unsigned short tmp[16];
      #pragma unroll
      for (int i = 0; i < 16; ++i) tmp[i] = f2bf(src[(size_t)i * NU]);
      #pragma unroll
      for (int h = 0; h < 2; ++h) {
        bf16x8 pv;
        #pragma unroll
        for (int j = 0; j < 8; ++j) pv[j] = (short)tmp[h * 8 + j];
        *(bf16x8*)&Bs[srow][shalf * 16 + h * 8] = pv;
      }
    }
    __syncthreads();

    bf16x8 af[4], bfr[4];
    #pragma unroll
    for (int mf = 0; mf < 4; ++mf)
      af[mf] = *(const bf16x8*)&As[wr * 64 + mf * 16 + l15][lk * 8];
    #pragma unroll
    for (int nf = 0; nf < 4; ++nf)
      bfr[nf] = *(const bf16x8*)&Bs[wc * 64 + nf * 16 + l15][lk * 8];
    #pragma unroll
    for (int mf = 0; mf < 4; ++mf)
      #pragma unroll
      for (int nf = 0; nf < 4; ++nf)
        acc[mf][nf] = __builtin_amdgcn_mfma_f32_16x16x32_bf16(af[mf], bfr[nf], acc[mf][nf], 0, 0, 0);
  }

  #pragma unroll
  for (int nf = 0; nf < 4; ++nf) {
    const int col = u0 + wc * 64 + nf * 16 + l15;
    const float bv = bias[col];
    #pragma unroll
    for (int mf = 0; mf < 4; ++mf) {
      const int rbase = m_base + wr * 64 + mf * 16 + lk * 4;
      #pragma unroll
      for (int r = 0; r < 4; ++r)
        xp[(size_t)(rbase + r) * NU + col] = acc[mf][nf][r] + bv;
    }
  }
}

// ---------------- persistent recurrent scan ----------------
// 32 WGs x 512 threads. WG owns 32 output columns. W_h slice lives in VGPRs
// (B-fragments, loaded once). h exchanged via relaxed agent-scope (sc1)
// atomics -> no L2 flush/invalidate needed. One monotonic-counter barrier/step.
__launch_bounds__(512, 1)
__global__ void scan_kernel(const float* __restrict__ Wh, const float* __restrict__ xp,
                            unsigned short* __restrict__ hbuf, float* __restrict__ out,
                            unsigned* __restrict__ bar, int t0, int Tc, int base) {
  __shared__ float Red[4][2][32][36];       // [k4][m2][col][row(+pad)] f32 partials
  __shared__ unsigned short Hout[64][36];   // staged h_next tile (row-major)

  const int tid = threadIdx.x;
  const int wid = blockIdx.x;   // 0..31
  const int col0 = wid * 32;
  const int lane = tid & 63;
  const int w = tid >> 6;       // 0..7
  const int k4 = w & 3;         // K-group: k in [k4*256, +256)
  const int m2 = w >> 2;        // M-half: rows [m2*32, +32)
  const int l15 = lane & 15;
  const int lk = lane >> 4;

  // ---- load persistent W_h B-fragments into VGPRs (one time) ----
  bf16x8 Bf[2][8];  // [nf][kq]
  #pragma unroll
  for (int nf = 0; nf < 2; ++nf)
    for (int kq = 0; kq < 8; ++kq) {
      const int kk = k4 * 8 + kq;
      const int col = col0 + nf * 16 + l15;
      bf16x8 v;
      #pragma unroll
      for (int j = 0; j < 8; ++j) {
        const int k = kk * 32 + lk * 8 + j;
        v[j] = (short)f2bf(Wh[(size_t)k * NU + col]);
      }
      Bf[nf][kq] = v;
    }

  // reduce-phase mapping: thread -> (local col, 4 rows)
  const int rcol = tid >> 4;            // 0..31
  const int rg = tid & 15;
  const int rm = rg >> 3;               // m-half
  const int rl = (rg & 7) * 4;          // row within half
  const int rrow = rm * 32 + rl;        // global row base

  // store-phase mapping: thread -> (row, 4-col group)
  const int srow = tid >> 3;            // 0..63
  const int scg = tid & 7;              // 0..7

  unsigned* cnt = bar;

  for (int tc = 0; tc < Tc; ++tc) {
    const int t = t0 + tc;
    const unsigned short* hc = hbuf + (size_t)(t & 1) * (NB * NU);
    unsigned short* hn = hbuf + (size_t)((t + 1) & 1) * (NB * NU);

    // prefetch xp for the reduce phase (independent of h)
    float xpv[4];
    #pragma unroll
    for (int r = 0; r < 4; ++r)
      xpv[r] = xp[((size_t)(rrow + r) * Tc + tc) * NU + col0 + rcol];

    // ---- MFMA phase: A (h) via relaxed agent loads, B from VGPRs ----
    f32x4 acc[2][2];
    #pragma unroll
    for (int mf = 0; mf < 2; ++mf)
      #pragma unroll
      for (int nf = 0; nf < 2; ++nf)
        acc[mf][nf] = (f32x4){0.f, 0.f, 0.f, 0.f};

    #pragma unroll
    for (int kq = 0; kq < 8; ++kq) {
      const int kk = k4 * 8 + kq;
      #pragma unroll
      for (int mf = 0; mf < 2; ++mf) {
        const int row = m2 * 32 + mf * 16 + l15;
        const u64* p = (const u64*)(hc + (size_t)row * NU + kk * 32 + lk * 8);
        const u64 q0 = __hip_atomic_load(p,     __ATOMIC_RELAXED, __HIP_MEMORY_SCOPE_AGENT);
        const u64 q1 = __hip_atomic_load(p + 1, __ATOMIC_RELAXED, __HIP_MEMORY_SCOPE_AGENT);
        union { u64 q[2]; bf16x8 v; } u; u.q[0] = q0; u.q[1] = q1;
        acc[mf][0] = __builtin_amdgcn_mfma_f32_16x16x32_bf16(u.v, Bf[0][kq], acc[mf][0], 0, 0, 0);
        acc[mf][1] = __builtin_amdgcn_mfma_f32_16x16x32_bf16(u.v, Bf[1][kq], acc[mf][1], 0, 0, 0);
      }
    }

    // write K-partials (col-major with row padding: 2-way banks only)
    #pragma unroll
    for (int mf = 0; mf < 2; ++mf)
      #pragma unroll
      for (int nf = 0; nf < 2; ++nf)
        *(f32x4*)&Red[k4][m2][nf * 16 + l15][mf * 16 + lk * 4] = acc[mf][nf];
    __syncthreads();

    // ---- reduce + xp + tanh -> Hout ----
    {
      f32x4 s = *(const f32x4*)&Red[0][rm][rcol][rl];
      s += *(const f32x4*)&Red[1][rm][rcol][rl];
      s += *(const f32x4*)&Red[2][rm][rcol][rl];
      s += *(const f32x4*)&Red[3][rm][rcol][rl];
      #pragma unroll
      for (int r = 0; r < 4; ++r) {
        const float hv = tanhf(s[r] + xpv[r]);
        Hout[rrow + r][rcol] = f2bf(hv);
        if (t == NT - 1) out[(size_t)(rrow + r) * NU + col0 + rcol] = hv;
      }
    }
    __syncthreads();

    // ---- coalesced h store (8B relaxed agent atomics -> coherence point) ----
    {
      const u64 hq = *(const u64*)&Hout[srow][scg * 4];
      __hip_atomic_store((u64*)(hn + (size_t)srow * NU + col0 + scg * 4), hq,
                         __ATOMIC_RELAXED, __HIP_MEMORY_SCOPE_AGENT);
    }

    if (tc != Tc - 1) {
      __syncthreads();  // vmcnt(0) drain before barrier: h stores are visible
      if (tid == 0) {
        __hip_atomic_fetch_add(cnt, 1u, __ATOMIC_RELAXED, __HIP_MEMORY_SCOPE_AGENT);
        const unsigned target = 32u * (unsigned)(base + tc + 1);
        while (__hip_atomic_load(cnt, __ATOMIC_RELAXED, __HIP_MEMORY_SCOPE_AGENT) < target) {}
        (void)__hip_atomic_load(cnt, __ATOMIC_ACQUIRE, __HIP_MEMORY_SCOPE_AGENT);
      }
      __syncthreads();
    }
  }
}

extern "C" void kernel_launch(void* const* d_in, const int* in_sizes, int n_in,
                              void* d_out, int out_size, void* d_ws, size_t ws_size,
                              hipStream_t stream) {
  (void)in_sizes; (void)n_in; (void)out_size;
  const float* inp  = (const float*)d_in[0];
  const float* Wx   = (const float*)d_in[1];
  const float* Wh   = (const float*)d_in[2];
  const float* bias = (const float*)d_in[3];
  float* out = (float*)d_out;

  unsigned* bar = (unsigned*)d_ws;                                   // 4 KB barrier area
  unsigned short* hbuf = (unsigned short*)((char*)d_ws + 4096);      // 256 KB h double-buffer
  const size_t xp_off = 4096 + (size_t)2 * NB * NU * sizeof(unsigned short);
  float* xp = (float*)((char*)d_ws + xp_off);
  const size_t avail = (ws_size > xp_off) ? ws_size - xp_off : 0;

  int Tc = 128;
  for (int cand = NT; cand >= 128; cand >>= 1)
    if ((size_t)NB * (size_t)cand * NU * sizeof(float) <= avail) { Tc = cand; break; }

  init_ws<<<dim3(128), dim3(256), 0, stream>>>((unsigned*)d_ws);

  for (int t0 = 0; t0 < NT; t0 += Tc) {
    const int base = (t0 / Tc) * (Tc - 1);
    gemm_xp<<<dim3(8, (NB * Tc) / 128), dim3(256), 0, stream>>>(inp, Wx, bias, xp, t0, Tc);
    scan_kernel<<<dim3(32), dim3(512), 0, stream>>>(Wh, xp, hbuf, out, bar, t0, Tc, base);
  }
}